// Round 4
// baseline (517.979 us; speedup 1.0000x reference)
//
#include <hip/hip_runtime.h>
#include <math.h>

#define N_NODES 200000
#define BGRAPH  1024
#define HDIM    256
#define ODIM    128
#define TSTEPS  2

// ---------------------------------------------------------------------------
// k_prep: blocks 0..255 compute v[i] = W[i,:].att_src, u[i] = W[i,:].att_dst
//         blocks 256..260 compute segment bounds via binary search
__global__ __launch_bounds__(256) void k_prep(const float* __restrict__ W,
        const float* __restrict__ att_src, const float* __restrict__ att_dst,
        const int* __restrict__ batch, float* __restrict__ v, float* __restrict__ u,
        int* __restrict__ seg) {
    int t = threadIdx.x;
    if (blockIdx.x < 256) {
        int i = blockIdx.x;
        float w = W[(size_t)i * HDIM + t];
        __shared__ float r1[256], r2[256];
        r1[t] = w * att_src[t];
        r2[t] = w * att_dst[t];
        __syncthreads();
        for (int st = 128; st > 0; st >>= 1) {
            if (t < st) { r1[t] += r1[t + st]; r2[t] += r2[t + st]; }
            __syncthreads();
        }
        if (t == 0) { v[i] = r1[0]; u[i] = r2[0]; }
    } else {
        int b = (blockIdx.x - 256) * 256 + t;
        if (b > BGRAPH) return;
        if (b == BGRAPH) { seg[b] = N_NODES; return; }
        int lo = 0, hi = N_NODES;
        while (lo < hi) { int mid = (lo + hi) >> 1; if (batch[mid] < b) lo = mid + 1; else hi = mid; }
        seg[b] = lo;
    }
}

// ---------------------------------------------------------------------------
// k_passA: one block per graph. One x sweep: pool (stt0) + smax_b = max_i (x_i.v)
__global__ __launch_bounds__(256) void k_passA(const float* __restrict__ x,
        const int* __restrict__ seg, const float* __restrict__ v,
        float* __restrict__ stt, float* __restrict__ smax) {
    int b = blockIdx.x;
    int lo = seg[b], hi = seg[b + 1];
    int t = threadIdx.x, wave = t >> 6, lane = t & 63;
    float v0 = v[4 * lane + 0], v1 = v[4 * lane + 1], v2 = v[4 * lane + 2], v3 = v[4 * lane + 3];
    float p0 = 0.f, p1 = 0.f, p2 = 0.f, p3 = 0.f;
    float sm = -3.402823466e38f;
    int i = lo + wave;
    for (; i + 12 < hi; i += 16) {
        const float4 r0 = *(const float4*)(x + (size_t)i * HDIM + 4 * lane);
        const float4 r1 = *(const float4*)(x + (size_t)(i + 4) * HDIM + 4 * lane);
        const float4 r2 = *(const float4*)(x + (size_t)(i + 8) * HDIM + 4 * lane);
        const float4 r3 = *(const float4*)(x + (size_t)(i + 12) * HDIM + 4 * lane);
        p0 += r0.x + r1.x + r2.x + r3.x; p1 += r0.y + r1.y + r2.y + r3.y;
        p2 += r0.z + r1.z + r2.z + r3.z; p3 += r0.w + r1.w + r2.w + r3.w;
        float d0 = r0.x * v0 + r0.y * v1 + r0.z * v2 + r0.w * v3;
        float d1 = r1.x * v0 + r1.y * v1 + r1.z * v2 + r1.w * v3;
        float d2 = r2.x * v0 + r2.y * v1 + r2.z * v2 + r2.w * v3;
        float d3 = r3.x * v0 + r3.y * v1 + r3.z * v2 + r3.w * v3;
        #pragma unroll
        for (int off = 1; off < 64; off <<= 1) {
            d0 += __shfl_xor(d0, off, 64);
            d1 += __shfl_xor(d1, off, 64);
            d2 += __shfl_xor(d2, off, 64);
            d3 += __shfl_xor(d3, off, 64);
        }
        sm = fmaxf(sm, fmaxf(fmaxf(d0, d1), fmaxf(d2, d3)));
    }
    for (; i < hi; i += 4) {
        const float4 r0 = *(const float4*)(x + (size_t)i * HDIM + 4 * lane);
        p0 += r0.x; p1 += r0.y; p2 += r0.z; p3 += r0.w;
        float d0 = r0.x * v0 + r0.y * v1 + r0.z * v2 + r0.w * v3;
        #pragma unroll
        for (int off = 1; off < 64; off <<= 1) d0 += __shfl_xor(d0, off, 64);
        sm = fmaxf(sm, d0);
    }
    __shared__ float comb[4][HDIM];
    comb[wave][4 * lane + 0] = p0; comb[wave][4 * lane + 1] = p1;
    comb[wave][4 * lane + 2] = p2; comb[wave][4 * lane + 3] = p3;
    __shared__ float sred[4];
    if (lane == 0) sred[wave] = sm;
    __syncthreads();
    stt[(size_t)b * HDIM + t] = comb[0][t] + comb[1][t] + comb[2][t] + comb[3][t];
    if (t == 0) smax[b] = fmaxf(fmaxf(sred[0], sred[1]), fmaxf(sred[2], sred[3]));
}

// ---------------------------------------------------------------------------
// k_iter_h: one block per graph b.
//  DO_GRU: first apply GRU(gi_b, gh_b, stt_b) -> stt_b (in-place, row-exclusive)
//  then d = stt_b.u ; M = leaky(smax_b + d)
//  single x sweep: s_i = x_i.v (butterfly), w_i = exp(leaky(s_i+d)-M),
//                  denom += w_i, agg += w_i * x_i
//  then aggx = agg/denom ; h_b = elu(aggx @ W + bias_gat) -> hbuf
template<int DO_GRU>
__global__ __launch_bounds__(256) void k_iter_h(const float* __restrict__ x,
        const int* __restrict__ seg, const float* __restrict__ v,
        const float* __restrict__ u, const float* __restrict__ smax,
        float* __restrict__ stt,
        const float* __restrict__ gi, const float* __restrict__ gh,
        const float* __restrict__ b_ih, const float* __restrict__ b_hh,
        const float* __restrict__ W, const float* __restrict__ bias_gat,
        float* __restrict__ hbuf) {
    int b = blockIdx.x, t = threadIdx.x;
    int lo = seg[b], hi = seg[b + 1];
    float st_j;
    if (DO_GRU) {
        size_t base = (size_t)b * (3 * HDIM);
        float gir = gi[base + t] + b_ih[t];
        float giz = gi[base + HDIM + t] + b_ih[HDIM + t];
        float gin = gi[base + 2 * HDIM + t] + b_ih[2 * HDIM + t];
        float ghr = gh[base + t] + b_hh[t];
        float ghz = gh[base + HDIM + t] + b_hh[HDIM + t];
        float ghn = gh[base + 2 * HDIM + t] + b_hh[2 * HDIM + t];
        float r = 1.f / (1.f + __expf(-(gir + ghr)));
        float z = 1.f / (1.f + __expf(-(giz + ghz)));
        float n = tanhf(gin + r * ghn);
        float prev = stt[(size_t)b * HDIM + t];
        float h2 = (1.f - z) * n + z * prev;
        st_j = h2 / (1.f + __expf(-h2));
        stt[(size_t)b * HDIM + t] = st_j;
    } else {
        st_j = stt[(size_t)b * HDIM + t];
    }
    __shared__ float red[256];
    red[t] = st_j * u[t];
    __syncthreads();
    for (int st = 128; st > 0; st >>= 1) { if (t < st) red[t] += red[t + st]; __syncthreads(); }
    float datt = red[0];
    __syncthreads();
    float M = smax[b] + datt;
    M = M > 0.f ? M : 0.01f * M;

    int wave = t >> 6, lane = t & 63;
    float v0 = v[4 * lane + 0], v1 = v[4 * lane + 1], v2 = v[4 * lane + 2], v3 = v[4 * lane + 3];
    float a0 = 0.f, a1 = 0.f, a2 = 0.f, a3 = 0.f, den = 0.f;
    int i = lo + wave;
    for (; i + 12 < hi; i += 16) {
        const float4 r0 = *(const float4*)(x + (size_t)i * HDIM + 4 * lane);
        const float4 r1 = *(const float4*)(x + (size_t)(i + 4) * HDIM + 4 * lane);
        const float4 r2 = *(const float4*)(x + (size_t)(i + 8) * HDIM + 4 * lane);
        const float4 r3 = *(const float4*)(x + (size_t)(i + 12) * HDIM + 4 * lane);
        float d0 = r0.x * v0 + r0.y * v1 + r0.z * v2 + r0.w * v3;
        float d1 = r1.x * v0 + r1.y * v1 + r1.z * v2 + r1.w * v3;
        float d2 = r2.x * v0 + r2.y * v1 + r2.z * v2 + r2.w * v3;
        float d3 = r3.x * v0 + r3.y * v1 + r3.z * v2 + r3.w * v3;
        #pragma unroll
        for (int off = 1; off < 64; off <<= 1) {
            d0 += __shfl_xor(d0, off, 64);
            d1 += __shfl_xor(d1, off, 64);
            d2 += __shfl_xor(d2, off, 64);
            d3 += __shfl_xor(d3, off, 64);
        }
        float e0 = d0 + datt; e0 = e0 > 0.f ? e0 : 0.01f * e0;
        float e1 = d1 + datt; e1 = e1 > 0.f ? e1 : 0.01f * e1;
        float e2 = d2 + datt; e2 = e2 > 0.f ? e2 : 0.01f * e2;
        float e3 = d3 + datt; e3 = e3 > 0.f ? e3 : 0.01f * e3;
        float w0 = __expf(e0 - M), w1 = __expf(e1 - M);
        float w2 = __expf(e2 - M), w3 = __expf(e3 - M);
        den += (w0 + w1) + (w2 + w3);
        a0 += w0 * r0.x + w1 * r1.x + w2 * r2.x + w3 * r3.x;
        a1 += w0 * r0.y + w1 * r1.y + w2 * r2.y + w3 * r3.y;
        a2 += w0 * r0.z + w1 * r1.z + w2 * r2.z + w3 * r3.z;
        a3 += w0 * r0.w + w1 * r1.w + w2 * r2.w + w3 * r3.w;
    }
    for (; i < hi; i += 4) {
        const float4 r0 = *(const float4*)(x + (size_t)i * HDIM + 4 * lane);
        float d0 = r0.x * v0 + r0.y * v1 + r0.z * v2 + r0.w * v3;
        #pragma unroll
        for (int off = 1; off < 64; off <<= 1) d0 += __shfl_xor(d0, off, 64);
        float e0 = d0 + datt; e0 = e0 > 0.f ? e0 : 0.01f * e0;
        float w0 = __expf(e0 - M);
        den += w0;
        a0 += w0 * r0.x; a1 += w0 * r0.y; a2 += w0 * r0.z; a3 += w0 * r0.w;
    }
    __shared__ float comb[4][HDIM];
    __shared__ float dred[4];
    comb[wave][4 * lane + 0] = a0; comb[wave][4 * lane + 1] = a1;
    comb[wave][4 * lane + 2] = a2; comb[wave][4 * lane + 3] = a3;
    if (lane == 0) dred[wave] = den;
    __syncthreads();
    float dtot = dred[0] + dred[1] + dred[2] + dred[3];
    float inv = (hi > lo) ? 1.0f / dtot : 0.f;
    __shared__ float ax[HDIM];
    ax[t] = (comb[0][t] + comb[1][t] + comb[2][t] + comb[3][t]) * inv;
    __syncthreads();
    float acc = bias_gat[t];
    #pragma unroll 8
    for (int ii = 0; ii < HDIM; ++ii) acc += ax[ii] * W[(size_t)ii * HDIM + t];
    hbuf[(size_t)b * HDIM + t] = acc > 0.f ? acc : expm1f(acc);
}

// ---------------------------------------------------------------------------
// Dual GEMM: gi = h @ W_ih^T (z=0), gh = stt @ W_hh^T (z=1). No bias (added later).
__global__ __launch_bounds__(256) void k_gemm2(const float* __restrict__ A0,
        const float* __restrict__ A1, const float* __restrict__ B0,
        const float* __restrict__ B1, float* __restrict__ C0, float* __restrict__ C1,
        int M, int N, int K) {
    const float* A = blockIdx.z ? A1 : A0;
    const float* B = blockIdx.z ? B1 : B0;
    float* C = blockIdx.z ? C1 : C0;
    __shared__ __align__(16) float As[16][64];
    __shared__ __align__(16) float Bs[16][64];
    int tx = threadIdx.x & 15, ty = threadIdx.x >> 4;
    int m0 = blockIdx.x * 64, n0 = blockIdx.y * 64;
    float acc[4][4] = {};
    for (int k0 = 0; k0 < K; k0 += 16) {
        {
            int r = threadIdx.x >> 2;
            int kk = (threadIdx.x & 3) << 2;
            float4 av = *(const float4*)(A + (size_t)(m0 + r) * K + k0 + kk);
            As[kk + 0][r] = av.x; As[kk + 1][r] = av.y;
            As[kk + 2][r] = av.z; As[kk + 3][r] = av.w;
            float4 bv = *(const float4*)(B + (size_t)(n0 + r) * K + k0 + kk);
            Bs[kk + 0][r] = bv.x; Bs[kk + 1][r] = bv.y;
            Bs[kk + 2][r] = bv.z; Bs[kk + 3][r] = bv.w;
        }
        __syncthreads();
        #pragma unroll
        for (int kk = 0; kk < 16; ++kk) {
            float4 a = *(const float4*)&As[kk][ty * 4];
            float4 bb = *(const float4*)&Bs[kk][tx * 4];
            acc[0][0] += a.x * bb.x; acc[0][1] += a.x * bb.y; acc[0][2] += a.x * bb.z; acc[0][3] += a.x * bb.w;
            acc[1][0] += a.y * bb.x; acc[1][1] += a.y * bb.y; acc[1][2] += a.y * bb.z; acc[1][3] += a.y * bb.w;
            acc[2][0] += a.z * bb.x; acc[2][1] += a.z * bb.y; acc[2][2] += a.z * bb.z; acc[2][3] += a.z * bb.w;
            acc[3][0] += a.w * bb.x; acc[3][1] += a.w * bb.y; acc[3][2] += a.w * bb.z; acc[3][3] += a.w * bb.w;
        }
        __syncthreads();
    }
    #pragma unroll
    for (int i = 0; i < 4; ++i) {
        int mrow = m0 + ty * 4 + i;
        *(float4*)(C + (size_t)mrow * N + n0 + tx * 4) =
            make_float4(acc[i][0], acc[i][1], acc[i][2], acc[i][3]);
    }
}

// ---------------------------------------------------------------------------
// Final: out = GRU(gi, gh, stt) @ W_lin + b_lin.  GRU applied in the A-tile loader.
__global__ __launch_bounds__(256) void k_final(const float* __restrict__ gi,
        const float* __restrict__ gh, const float* __restrict__ b_ih,
        const float* __restrict__ b_hh, const float* __restrict__ stt,
        const float* __restrict__ B, const float* __restrict__ bias,
        float* __restrict__ C, int M, int N, int K) {
    __shared__ __align__(16) float As[16][64];
    __shared__ __align__(16) float Bs[16][64];
    int tx = threadIdx.x & 15, ty = threadIdx.x >> 4;
    int m0 = blockIdx.x * 64, n0 = blockIdx.y * 64;
    float acc[4][4] = {};
    for (int k0 = 0; k0 < K; k0 += 16) {
        {
            int r = threadIdx.x >> 2;
            int kk0 = (threadIdx.x & 3) << 2;
            int mrow = m0 + r;
            size_t base = (size_t)mrow * (3 * HDIM);
            #pragma unroll
            for (int q = 0; q < 4; ++q) {
                int k = k0 + kk0 + q;
                float gir = gi[base + k] + b_ih[k];
                float giz = gi[base + HDIM + k] + b_ih[HDIM + k];
                float gin = gi[base + 2 * HDIM + k] + b_ih[2 * HDIM + k];
                float ghr = gh[base + k] + b_hh[k];
                float ghz = gh[base + HDIM + k] + b_hh[HDIM + k];
                float ghn = gh[base + 2 * HDIM + k] + b_hh[2 * HDIM + k];
                float rg = 1.f / (1.f + __expf(-(gir + ghr)));
                float zg = 1.f / (1.f + __expf(-(giz + ghz)));
                float ng = tanhf(gin + rg * ghn);
                float prev = stt[(size_t)mrow * HDIM + k];
                float h2 = (1.f - zg) * ng + zg * prev;
                As[kk0 + q][r] = h2 / (1.f + __expf(-h2));
            }
        }
        {
            int kk = threadIdx.x >> 4;
            int nn = (threadIdx.x & 15) << 2;
            float4 bv = *(const float4*)(B + (size_t)(k0 + kk) * N + n0 + nn);
            Bs[kk][nn + 0] = bv.x; Bs[kk][nn + 1] = bv.y;
            Bs[kk][nn + 2] = bv.z; Bs[kk][nn + 3] = bv.w;
        }
        __syncthreads();
        #pragma unroll
        for (int kk = 0; kk < 16; ++kk) {
            float4 a = *(const float4*)&As[kk][ty * 4];
            float4 bb = *(const float4*)&Bs[kk][tx * 4];
            acc[0][0] += a.x * bb.x; acc[0][1] += a.x * bb.y; acc[0][2] += a.x * bb.z; acc[0][3] += a.x * bb.w;
            acc[1][0] += a.y * bb.x; acc[1][1] += a.y * bb.y; acc[1][2] += a.y * bb.z; acc[1][3] += a.y * bb.w;
            acc[2][0] += a.z * bb.x; acc[2][1] += a.z * bb.y; acc[2][2] += a.z * bb.z; acc[2][3] += a.z * bb.w;
            acc[3][0] += a.w * bb.x; acc[3][1] += a.w * bb.y; acc[3][2] += a.w * bb.z; acc[3][3] += a.w * bb.w;
        }
        __syncthreads();
    }
    float bsv[4];
    #pragma unroll
    for (int j = 0; j < 4; ++j) bsv[j] = bias[n0 + tx * 4 + j];
    #pragma unroll
    for (int i = 0; i < 4; ++i) {
        int mrow = m0 + ty * 4 + i;
        *(float4*)(C + (size_t)mrow * N + n0 + tx * 4) =
            make_float4(acc[i][0] + bsv[0], acc[i][1] + bsv[1],
                        acc[i][2] + bsv[2], acc[i][3] + bsv[3]);
    }
}

extern "C" void kernel_launch(void* const* d_in, const int* in_sizes, int n_in,
                              void* d_out, int out_size, void* d_ws, size_t ws_size,
                              hipStream_t stream) {
    const float* x        = (const float*)d_in[0];
    const int*   batch    = (const int*)d_in[1];
    const float* W        = (const float*)d_in[2];
    const float* att_src  = (const float*)d_in[3];
    const float* att_dst  = (const float*)d_in[4];
    const float* bias_gat = (const float*)d_in[5];
    const float* W_ih     = (const float*)d_in[6];
    const float* W_hh     = (const float*)d_in[7];
    const float* b_ih     = (const float*)d_in[8];
    const float* b_hh     = (const float*)d_in[9];
    const float* W_lin    = (const float*)d_in[10];
    const float* b_lin    = (const float*)d_in[11];

    char* ws = (char*)d_ws;
    size_t off = 0;
    auto alloc = [&](size_t bytes) {
        void* p = (void*)(ws + off);
        off += (bytes + 255) & ~(size_t)255;
        return p;
    };
    int*   seg  = (int*)alloc((BGRAPH + 1) * 4);
    float* vv   = (float*)alloc(HDIM * 4);
    float* uu   = (float*)alloc(HDIM * 4);
    float* smax = (float*)alloc(BGRAPH * 4);
    float* stt  = (float*)alloc((size_t)BGRAPH * HDIM * 4);
    float* hbuf = (float*)alloc((size_t)BGRAPH * HDIM * 4);
    float* gi   = (float*)alloc((size_t)BGRAPH * 3 * HDIM * 4);
    float* gh   = (float*)alloc((size_t)BGRAPH * 3 * HDIM * 4);

    hipLaunchKernelGGL(k_prep, dim3(261), dim3(256), 0, stream,
                       W, att_src, att_dst, batch, vv, uu, seg);
    hipLaunchKernelGGL(k_passA, dim3(BGRAPH), dim3(256), 0, stream, x, seg, vv, stt, smax);

    // tstep 1 (no GRU at head)
    hipLaunchKernelGGL((k_iter_h<0>), dim3(BGRAPH), dim3(256), 0, stream,
                       x, seg, vv, uu, smax, stt, (const float*)nullptr, (const float*)nullptr,
                       b_ih, b_hh, W, bias_gat, hbuf);
    hipLaunchKernelGGL(k_gemm2, dim3(BGRAPH / 64, (3 * HDIM) / 64, 2), dim3(256), 0,
                       stream, hbuf, stt, W_ih, W_hh, gi, gh, BGRAPH, 3 * HDIM, HDIM);
    // tstep 2 (GRU folded into head)
    hipLaunchKernelGGL((k_iter_h<1>), dim3(BGRAPH), dim3(256), 0, stream,
                       x, seg, vv, uu, smax, stt, gi, gh,
                       b_ih, b_hh, W, bias_gat, hbuf);
    hipLaunchKernelGGL(k_gemm2, dim3(BGRAPH / 64, (3 * HDIM) / 64, 2), dim3(256), 0,
                       stream, hbuf, stt, W_ih, W_hh, gi, gh, BGRAPH, 3 * HDIM, HDIM);
    // final: GRU folded into A-loader, then @ W_lin + b_lin
    hipLaunchKernelGGL(k_final, dim3(BGRAPH / 64, ODIM / 64), dim3(256), 0, stream,
                       gi, gh, b_ih, b_hh, stt, W_lin, b_lin, (float*)d_out,
                       BGRAPH, ODIM, HDIM);
}

// Round 5
// 507.994 us; speedup vs baseline: 1.0197x; 1.0197x over previous
//
#include <hip/hip_runtime.h>
#include <math.h>

#define N_NODES 200000
#define BGRAPH  1024
#define HDIM    256
#define ODIM    128
#define SCAP    1024   // max segment length cached in LDS (actual max ~250)

// ---------------------------------------------------------------------------
// k_prep: blocks 0..255: v[i] = W[i,:].att_src, u[i] = W[i,:].att_dst
//         blocks 256..260: segment bounds via binary search (batch sorted)
__global__ __launch_bounds__(256) void k_prep(const float* __restrict__ W,
        const float* __restrict__ att_src, const float* __restrict__ att_dst,
        const int* __restrict__ batch, float* __restrict__ v, float* __restrict__ u,
        int* __restrict__ seg) {
    int t = threadIdx.x;
    if (blockIdx.x < 256) {
        int i = blockIdx.x;
        float w = W[(size_t)i * HDIM + t];
        __shared__ float r1[256], r2[256];
        r1[t] = w * att_src[t];
        r2[t] = w * att_dst[t];
        __syncthreads();
        for (int st = 128; st > 0; st >>= 1) {
            if (t < st) { r1[t] += r1[t + st]; r2[t] += r2[t + st]; }
            __syncthreads();
        }
        if (t == 0) { v[i] = r1[0]; u[i] = r2[0]; }
    } else {
        int b = (blockIdx.x - 256) * 256 + t;
        if (b > BGRAPH) return;
        if (b == BGRAPH) { seg[b] = N_NODES; return; }
        int lo = 0, hi = N_NODES;
        while (lo < hi) { int mid = (lo + hi) >> 1; if (batch[mid] < b) lo = mid + 1; else hi = mid; }
        seg[b] = lo;
    }
}

// ---------------------------------------------------------------------------
// k_passAB: one block per graph b. Fused:
//  pass 1 (x from HBM): pool -> state0_b, s_i = x_i.v (shfl_down reduce, lane0
//          writes s[] global + LDS stash), smax_b
//  then d1 = state0_b.u, M1 = leaky(smax_b + d1)
//  pass 2 (x from L2, s from LDS): w_i = exp(leaky(s_i+d1)-M1), den += w_i,
//          agg += w_i * x_i ; h1_b = elu((agg/den) @ W + bias_gat) -> hbuf
__global__ __launch_bounds__(256) void k_passAB(const float* __restrict__ x,
        const int* __restrict__ seg, const float* __restrict__ v,
        const float* __restrict__ u, const float* __restrict__ W,
        const float* __restrict__ bias_gat,
        float* __restrict__ s, float* __restrict__ smax,
        float* __restrict__ stt, float* __restrict__ hbuf) {
    int b = blockIdx.x;
    int lo = seg[b], hi = seg[b + 1];
    int t = threadIdx.x, wave = t >> 6, lane = t & 63;
    float v0 = v[4 * lane + 0], v1 = v[4 * lane + 1], v2 = v[4 * lane + 2], v3 = v[4 * lane + 3];
    __shared__ float s_loc[SCAP];
    __shared__ float comb[4][HDIM];
    __shared__ float red[256];
    __shared__ float sred[4], dred[4];
    bool inl = (hi - lo) <= SCAP;

    // ---- pass 1: pool + s + smax ----
    float p0 = 0.f, p1 = 0.f, p2 = 0.f, p3 = 0.f;
    float sm = -3.402823466e38f;
    int i = lo + wave;
    for (; i + 4 < hi; i += 8) {
        const float4 r0 = *(const float4*)(x + (size_t)i * HDIM + 4 * lane);
        const float4 r1 = *(const float4*)(x + (size_t)(i + 4) * HDIM + 4 * lane);
        p0 += r0.x + r1.x; p1 += r0.y + r1.y; p2 += r0.z + r1.z; p3 += r0.w + r1.w;
        float pa = r0.x * v0 + r0.y * v1 + r0.z * v2 + r0.w * v3;
        float pb = r1.x * v0 + r1.y * v1 + r1.z * v2 + r1.w * v3;
        #pragma unroll
        for (int off = 32; off > 0; off >>= 1) {
            pa += __shfl_down(pa, off, 64);
            pb += __shfl_down(pb, off, 64);
        }
        if (lane == 0) {
            s[i] = pa; s[i + 4] = pb;
            if (inl) { s_loc[i - lo] = pa; s_loc[i + 4 - lo] = pb; }
            sm = fmaxf(sm, fmaxf(pa, pb));
        }
    }
    for (; i < hi; i += 4) {
        const float4 r0 = *(const float4*)(x + (size_t)i * HDIM + 4 * lane);
        p0 += r0.x; p1 += r0.y; p2 += r0.z; p3 += r0.w;
        float pa = r0.x * v0 + r0.y * v1 + r0.z * v2 + r0.w * v3;
        #pragma unroll
        for (int off = 32; off > 0; off >>= 1) pa += __shfl_down(pa, off, 64);
        if (lane == 0) {
            s[i] = pa;
            if (inl) s_loc[i - lo] = pa;
            sm = fmaxf(sm, pa);
        }
    }
    comb[wave][4 * lane + 0] = p0; comb[wave][4 * lane + 1] = p1;
    comb[wave][4 * lane + 2] = p2; comb[wave][4 * lane + 3] = p3;
    if (lane == 0) sred[wave] = sm;
    __syncthreads();
    float st0 = comb[0][t] + comb[1][t] + comb[2][t] + comb[3][t];
    stt[(size_t)b * HDIM + t] = st0;
    float smx = fmaxf(fmaxf(sred[0], sred[1]), fmaxf(sred[2], sred[3]));
    if (t == 0) smax[b] = smx;
    // d1 = state0 . u
    red[t] = st0 * u[t];
    __syncthreads();
    for (int st = 128; st > 0; st >>= 1) { if (t < st) red[t] += red[t + st]; __syncthreads(); }
    float d1 = red[0];
    __syncthreads();
    float M = smx + d1;
    M = M > 0.f ? M : 0.01f * M;

    // ---- pass 2: weighted aggregation (x L2-hot, s from LDS) ----
    float a0 = 0.f, a1 = 0.f, a2 = 0.f, a3 = 0.f, den = 0.f;
    i = lo + wave;
    for (; i + 4 < hi; i += 8) {
        float s0v = inl ? s_loc[i - lo]     : s[i];
        float s1v = inl ? s_loc[i + 4 - lo] : s[i + 4];
        float e0 = s0v + d1; e0 = e0 > 0.f ? e0 : 0.01f * e0;
        float e1 = s1v + d1; e1 = e1 > 0.f ? e1 : 0.01f * e1;
        float w0 = __expf(e0 - M), w1 = __expf(e1 - M);
        const float4 r0 = *(const float4*)(x + (size_t)i * HDIM + 4 * lane);
        const float4 r1 = *(const float4*)(x + (size_t)(i + 4) * HDIM + 4 * lane);
        den += w0 + w1;
        a0 += w0 * r0.x + w1 * r1.x; a1 += w0 * r0.y + w1 * r1.y;
        a2 += w0 * r0.z + w1 * r1.z; a3 += w0 * r0.w + w1 * r1.w;
    }
    for (; i < hi; i += 4) {
        float s0v = inl ? s_loc[i - lo] : s[i];
        float e0 = s0v + d1; e0 = e0 > 0.f ? e0 : 0.01f * e0;
        float w0 = __expf(e0 - M);
        const float4 r0 = *(const float4*)(x + (size_t)i * HDIM + 4 * lane);
        den += w0;
        a0 += w0 * r0.x; a1 += w0 * r0.y; a2 += w0 * r0.z; a3 += w0 * r0.w;
    }
    __syncthreads();  // re-use comb
    comb[wave][4 * lane + 0] = a0; comb[wave][4 * lane + 1] = a1;
    comb[wave][4 * lane + 2] = a2; comb[wave][4 * lane + 3] = a3;
    if (lane == 0) dred[wave] = den;
    __syncthreads();
    float dtot = dred[0] + dred[1] + dred[2] + dred[3];
    float inv = (hi > lo) ? 1.0f / dtot : 0.f;
    __shared__ float ax[HDIM];
    ax[t] = (comb[0][t] + comb[1][t] + comb[2][t] + comb[3][t]) * inv;
    __syncthreads();
    float acc = bias_gat[t];
    #pragma unroll 8
    for (int ii = 0; ii < HDIM; ++ii) acc += ax[ii] * W[(size_t)ii * HDIM + t];
    hbuf[(size_t)b * HDIM + t] = acc > 0.f ? acc : expm1f(acc);
}

// ---------------------------------------------------------------------------
// k_iter2: one block per graph b (timestep 2).
//  GRU(gi_b, gh_b, stt_b) -> state1 (in-place), d2 = state1.u,
//  M = leaky(smax_b + d2), sweep x reading precomputed s[] (no shuffles),
//  h2_b = elu((agg/den) @ W + bias_gat) -> hbuf
__global__ __launch_bounds__(256) void k_iter2(const float* __restrict__ x,
        const int* __restrict__ seg, const float* __restrict__ s,
        const float* __restrict__ u, const float* __restrict__ smax,
        float* __restrict__ stt,
        const float* __restrict__ gi, const float* __restrict__ gh,
        const float* __restrict__ b_ih, const float* __restrict__ b_hh,
        const float* __restrict__ W, const float* __restrict__ bias_gat,
        float* __restrict__ hbuf) {
    int b = blockIdx.x, t = threadIdx.x;
    int lo = seg[b], hi = seg[b + 1];
    size_t base = (size_t)b * (3 * HDIM);
    float gir = gi[base + t] + b_ih[t];
    float giz = gi[base + HDIM + t] + b_ih[HDIM + t];
    float gin = gi[base + 2 * HDIM + t] + b_ih[2 * HDIM + t];
    float ghr = gh[base + t] + b_hh[t];
    float ghz = gh[base + HDIM + t] + b_hh[HDIM + t];
    float ghn = gh[base + 2 * HDIM + t] + b_hh[2 * HDIM + t];
    float r = 1.f / (1.f + __expf(-(gir + ghr)));
    float z = 1.f / (1.f + __expf(-(giz + ghz)));
    float n = tanhf(gin + r * ghn);
    float prev = stt[(size_t)b * HDIM + t];
    float h2 = (1.f - z) * n + z * prev;
    float st_j = h2 / (1.f + __expf(-h2));
    stt[(size_t)b * HDIM + t] = st_j;

    __shared__ float red[256];
    red[t] = st_j * u[t];
    __syncthreads();
    for (int st = 128; st > 0; st >>= 1) { if (t < st) red[t] += red[t + st]; __syncthreads(); }
    float d2 = red[0];
    __syncthreads();
    float M = smax[b] + d2;
    M = M > 0.f ? M : 0.01f * M;

    int wave = t >> 6, lane = t & 63;
    float a0 = 0.f, a1 = 0.f, a2 = 0.f, a3 = 0.f, den = 0.f;
    int i = lo + wave;
    for (; i + 4 < hi; i += 8) {
        float e0 = s[i] + d2;     e0 = e0 > 0.f ? e0 : 0.01f * e0;
        float e1 = s[i + 4] + d2; e1 = e1 > 0.f ? e1 : 0.01f * e1;
        float w0 = __expf(e0 - M), w1 = __expf(e1 - M);
        const float4 r0 = *(const float4*)(x + (size_t)i * HDIM + 4 * lane);
        const float4 r1 = *(const float4*)(x + (size_t)(i + 4) * HDIM + 4 * lane);
        den += w0 + w1;
        a0 += w0 * r0.x + w1 * r1.x; a1 += w0 * r0.y + w1 * r1.y;
        a2 += w0 * r0.z + w1 * r1.z; a3 += w0 * r0.w + w1 * r1.w;
    }
    for (; i < hi; i += 4) {
        float e0 = s[i] + d2; e0 = e0 > 0.f ? e0 : 0.01f * e0;
        float w0 = __expf(e0 - M);
        const float4 r0 = *(const float4*)(x + (size_t)i * HDIM + 4 * lane);
        den += w0;
        a0 += w0 * r0.x; a1 += w0 * r0.y; a2 += w0 * r0.z; a3 += w0 * r0.w;
    }
    __shared__ float comb[4][HDIM];
    __shared__ float dred[4];
    comb[wave][4 * lane + 0] = a0; comb[wave][4 * lane + 1] = a1;
    comb[wave][4 * lane + 2] = a2; comb[wave][4 * lane + 3] = a3;
    if (lane == 0) dred[wave] = den;
    __syncthreads();
    float dtot = dred[0] + dred[1] + dred[2] + dred[3];
    float inv = (hi > lo) ? 1.0f / dtot : 0.f;
    __shared__ float ax[HDIM];
    ax[t] = (comb[0][t] + comb[1][t] + comb[2][t] + comb[3][t]) * inv;
    __syncthreads();
    float acc = bias_gat[t];
    #pragma unroll 8
    for (int ii = 0; ii < HDIM; ++ii) acc += ax[ii] * W[(size_t)ii * HDIM + t];
    hbuf[(size_t)b * HDIM + t] = acc > 0.f ? acc : expm1f(acc);
}

// ---------------------------------------------------------------------------
// Dual GEMM: gi = h @ W_ih^T (z=0), gh = stt @ W_hh^T (z=1). Bias added later.
__global__ __launch_bounds__(256) void k_gemm2(const float* __restrict__ A0,
        const float* __restrict__ A1, const float* __restrict__ B0,
        const float* __restrict__ B1, float* __restrict__ C0, float* __restrict__ C1,
        int M, int N, int K) {
    const float* A = blockIdx.z ? A1 : A0;
    const float* B = blockIdx.z ? B1 : B0;
    float* C = blockIdx.z ? C1 : C0;
    __shared__ __align__(16) float As[16][64];
    __shared__ __align__(16) float Bs[16][64];
    int tx = threadIdx.x & 15, ty = threadIdx.x >> 4;
    int m0 = blockIdx.x * 64, n0 = blockIdx.y * 64;
    float acc[4][4] = {};
    for (int k0 = 0; k0 < K; k0 += 16) {
        {
            int r = threadIdx.x >> 2;
            int kk = (threadIdx.x & 3) << 2;
            float4 av = *(const float4*)(A + (size_t)(m0 + r) * K + k0 + kk);
            As[kk + 0][r] = av.x; As[kk + 1][r] = av.y;
            As[kk + 2][r] = av.z; As[kk + 3][r] = av.w;
            float4 bv = *(const float4*)(B + (size_t)(n0 + r) * K + k0 + kk);
            Bs[kk + 0][r] = bv.x; Bs[kk + 1][r] = bv.y;
            Bs[kk + 2][r] = bv.z; Bs[kk + 3][r] = bv.w;
        }
        __syncthreads();
        #pragma unroll
        for (int kk = 0; kk < 16; ++kk) {
            float4 a = *(const float4*)&As[kk][ty * 4];
            float4 bb = *(const float4*)&Bs[kk][tx * 4];
            acc[0][0] += a.x * bb.x; acc[0][1] += a.x * bb.y; acc[0][2] += a.x * bb.z; acc[0][3] += a.x * bb.w;
            acc[1][0] += a.y * bb.x; acc[1][1] += a.y * bb.y; acc[1][2] += a.y * bb.z; acc[1][3] += a.y * bb.w;
            acc[2][0] += a.z * bb.x; acc[2][1] += a.z * bb.y; acc[2][2] += a.z * bb.z; acc[2][3] += a.z * bb.w;
            acc[3][0] += a.w * bb.x; acc[3][1] += a.w * bb.y; acc[3][2] += a.w * bb.z; acc[3][3] += a.w * bb.w;
        }
        __syncthreads();
    }
    #pragma unroll
    for (int i = 0; i < 4; ++i) {
        int mrow = m0 + ty * 4 + i;
        *(float4*)(C + (size_t)mrow * N + n0 + tx * 4) =
            make_float4(acc[i][0], acc[i][1], acc[i][2], acc[i][3]);
    }
}

// ---------------------------------------------------------------------------
// Final: out = GRU(gi, gh, stt) @ W_lin + b_lin. GRU applied in the A-tile loader.
__global__ __launch_bounds__(256) void k_final(const float* __restrict__ gi,
        const float* __restrict__ gh, const float* __restrict__ b_ih,
        const float* __restrict__ b_hh, const float* __restrict__ stt,
        const float* __restrict__ B, const float* __restrict__ bias,
        float* __restrict__ C, int M, int N, int K) {
    __shared__ __align__(16) float As[16][64];
    __shared__ __align__(16) float Bs[16][64];
    int tx = threadIdx.x & 15, ty = threadIdx.x >> 4;
    int m0 = blockIdx.x * 64, n0 = blockIdx.y * 64;
    float acc[4][4] = {};
    for (int k0 = 0; k0 < K; k0 += 16) {
        {
            int r = threadIdx.x >> 2;
            int kk0 = (threadIdx.x & 3) << 2;
            int mrow = m0 + r;
            size_t base = (size_t)mrow * (3 * HDIM);
            #pragma unroll
            for (int q = 0; q < 4; ++q) {
                int k = k0 + kk0 + q;
                float gir = gi[base + k] + b_ih[k];
                float giz = gi[base + HDIM + k] + b_ih[HDIM + k];
                float gin = gi[base + 2 * HDIM + k] + b_ih[2 * HDIM + k];
                float ghr = gh[base + k] + b_hh[k];
                float ghz = gh[base + HDIM + k] + b_hh[HDIM + k];
                float ghn = gh[base + 2 * HDIM + k] + b_hh[2 * HDIM + k];
                float rg = 1.f / (1.f + __expf(-(gir + ghr)));
                float zg = 1.f / (1.f + __expf(-(giz + ghz)));
                float ng = tanhf(gin + rg * ghn);
                float prev = stt[(size_t)mrow * HDIM + k];
                float h2 = (1.f - zg) * ng + zg * prev;
                As[kk0 + q][r] = h2 / (1.f + __expf(-h2));
            }
        }
        {
            int kk = threadIdx.x >> 4;
            int nn = (threadIdx.x & 15) << 2;
            float4 bv = *(const float4*)(B + (size_t)(k0 + kk) * N + n0 + nn);
            Bs[kk][nn + 0] = bv.x; Bs[kk][nn + 1] = bv.y;
            Bs[kk][nn + 2] = bv.z; Bs[kk][nn + 3] = bv.w;
        }
        __syncthreads();
        #pragma unroll
        for (int kk = 0; kk < 16; ++kk) {
            float4 a = *(const float4*)&As[kk][ty * 4];
            float4 bb = *(const float4*)&Bs[kk][tx * 4];
            acc[0][0] += a.x * bb.x; acc[0][1] += a.x * bb.y; acc[0][2] += a.x * bb.z; acc[0][3] += a.x * bb.w;
            acc[1][0] += a.y * bb.x; acc[1][1] += a.y * bb.y; acc[1][2] += a.y * bb.z; acc[1][3] += a.y * bb.w;
            acc[2][0] += a.z * bb.x; acc[2][1] += a.z * bb.y; acc[2][2] += a.z * bb.z; acc[2][3] += a.z * bb.w;
            acc[3][0] += a.w * bb.x; acc[3][1] += a.w * bb.y; acc[3][2] += a.w * bb.z; acc[3][3] += a.w * bb.w;
        }
        __syncthreads();
    }
    float bsv[4];
    #pragma unroll
    for (int j = 0; j < 4; ++j) bsv[j] = bias[n0 + tx * 4 + j];
    #pragma unroll
    for (int i = 0; i < 4; ++i) {
        int mrow = m0 + ty * 4 + i;
        *(float4*)(C + (size_t)mrow * N + n0 + tx * 4) =
            make_float4(acc[i][0] + bsv[0], acc[i][1] + bsv[1],
                        acc[i][2] + bsv[2], acc[i][3] + bsv[3]);
    }
}

extern "C" void kernel_launch(void* const* d_in, const int* in_sizes, int n_in,
                              void* d_out, int out_size, void* d_ws, size_t ws_size,
                              hipStream_t stream) {
    const float* x        = (const float*)d_in[0];
    const int*   batch    = (const int*)d_in[1];
    const float* W        = (const float*)d_in[2];
    const float* att_src  = (const float*)d_in[3];
    const float* att_dst  = (const float*)d_in[4];
    const float* bias_gat = (const float*)d_in[5];
    const float* W_ih     = (const float*)d_in[6];
    const float* W_hh     = (const float*)d_in[7];
    const float* b_ih     = (const float*)d_in[8];
    const float* b_hh     = (const float*)d_in[9];
    const float* W_lin    = (const float*)d_in[10];
    const float* b_lin    = (const float*)d_in[11];

    char* ws = (char*)d_ws;
    size_t off = 0;
    auto alloc = [&](size_t bytes) {
        void* p = (void*)(ws + off);
        off += (bytes + 255) & ~(size_t)255;
        return p;
    };
    int*   seg  = (int*)alloc((BGRAPH + 1) * 4);
    float* vv   = (float*)alloc(HDIM * 4);
    float* uu   = (float*)alloc(HDIM * 4);
    float* smax = (float*)alloc(BGRAPH * 4);
    float* s    = (float*)alloc((size_t)N_NODES * 4);
    float* stt  = (float*)alloc((size_t)BGRAPH * HDIM * 4);
    float* hbuf = (float*)alloc((size_t)BGRAPH * HDIM * 4);
    float* gi   = (float*)alloc((size_t)BGRAPH * 3 * HDIM * 4);
    float* gh   = (float*)alloc((size_t)BGRAPH * 3 * HDIM * 4);

    hipLaunchKernelGGL(k_prep, dim3(261), dim3(256), 0, stream,
                       W, att_src, att_dst, batch, vv, uu, seg);
    // tstep 1 fully fused with pool pass
    hipLaunchKernelGGL(k_passAB, dim3(BGRAPH), dim3(256), 0, stream,
                       x, seg, vv, uu, W, bias_gat, s, smax, stt, hbuf);
    hipLaunchKernelGGL(k_gemm2, dim3(BGRAPH / 64, (3 * HDIM) / 64, 2), dim3(256), 0,
                       stream, hbuf, stt, W_ih, W_hh, gi, gh, BGRAPH, 3 * HDIM, HDIM);
    // tstep 2 (GRU folded into head, s precomputed)
    hipLaunchKernelGGL(k_iter2, dim3(BGRAPH), dim3(256), 0, stream,
                       x, seg, s, uu, smax, stt, gi, gh, b_ih, b_hh, W, bias_gat, hbuf);
    hipLaunchKernelGGL(k_gemm2, dim3(BGRAPH / 64, (3 * HDIM) / 64, 2), dim3(256), 0,
                       stream, hbuf, stt, W_ih, W_hh, gi, gh, BGRAPH, 3 * HDIM, HDIM);
    // final: GRU folded into A-loader, then @ W_lin + b_lin
    hipLaunchKernelGGL(k_final, dim3(BGRAPH / 64, ODIM / 64), dim3(256), 0, stream,
                       gi, gh, b_ih, b_hh, stt, W_lin, b_lin, (float*)d_out,
                       BGRAPH, ODIM, HDIM);
}

// Round 6
// 482.729 us; speedup vs baseline: 1.0730x; 1.0523x over previous
//
#include <hip/hip_runtime.h>
#include <math.h>

#define N_NODES 200000
#define BGRAPH  1024
#define HDIM    256
#define ODIM    128
#define SCAP    1024   // max segment length cached in LDS (actual max ~250)

typedef __attribute__((ext_vector_type(8))) short short8;
typedef __attribute__((ext_vector_type(4))) float f32x4;

__device__ __forceinline__ unsigned short f2bf(float f) {
    union { float f; unsigned int i; } c; c.f = f;
    unsigned int i = c.i;
    unsigned int r = i + 0x7FFFu + ((i >> 16) & 1u);  // RNE
    return (unsigned short)(r >> 16);
}

// ---------------------------------------------------------------------------
// k_prep: blocks 0..255: v[i] = W[i,:].att_src, u[i] = W[i,:].att_dst
//         blocks 256..260: segment bounds via binary search (batch sorted)
__global__ __launch_bounds__(256) void k_prep(const float* __restrict__ W,
        const float* __restrict__ att_src, const float* __restrict__ att_dst,
        const int* __restrict__ batch, float* __restrict__ v, float* __restrict__ u,
        int* __restrict__ seg) {
    int t = threadIdx.x;
    if (blockIdx.x < 256) {
        int i = blockIdx.x;
        float w = W[(size_t)i * HDIM + t];
        __shared__ float r1[256], r2[256];
        r1[t] = w * att_src[t];
        r2[t] = w * att_dst[t];
        __syncthreads();
        for (int st = 128; st > 0; st >>= 1) {
            if (t < st) { r1[t] += r1[t + st]; r2[t] += r2[t + st]; }
            __syncthreads();
        }
        if (t == 0) { v[i] = r1[0]; u[i] = r2[0]; }
    } else {
        int b = (blockIdx.x - 256) * 256 + t;
        if (b > BGRAPH) return;
        if (b == BGRAPH) { seg[b] = N_NODES; return; }
        int lo = 0, hi = N_NODES;
        while (lo < hi) { int mid = (lo + hi) >> 1; if (batch[mid] < b) lo = mid + 1; else hi = mid; }
        seg[b] = lo;
    }
}

// ---------------------------------------------------------------------------
// k_passAB: one block per graph b. Fused pool + s + smax (pass1, HBM) and
// tstep-1 weighted aggregation (pass2, L2/L3-hot) + h1 = elu(agg@W + bias).
__global__ __launch_bounds__(256) void k_passAB(const float* __restrict__ x,
        const int* __restrict__ seg, const float* __restrict__ v,
        const float* __restrict__ u, const float* __restrict__ W,
        const float* __restrict__ bias_gat,
        float* __restrict__ s, float* __restrict__ smax,
        float* __restrict__ stt, float* __restrict__ hbuf) {
    int b = blockIdx.x;
    int lo = seg[b], hi = seg[b + 1];
    int t = threadIdx.x, wave = t >> 6, lane = t & 63;
    float v0 = v[4 * lane + 0], v1 = v[4 * lane + 1], v2 = v[4 * lane + 2], v3 = v[4 * lane + 3];
    __shared__ float s_loc[SCAP];
    __shared__ float comb[4][HDIM];
    __shared__ float red[256];
    __shared__ float sred[4], dred[4];
    bool inl = (hi - lo) <= SCAP;

    // ---- pass 1: pool + s + smax ----
    float p0 = 0.f, p1 = 0.f, p2 = 0.f, p3 = 0.f;
    float sm = -3.402823466e38f;
    int i = lo + wave;
    for (; i + 4 < hi; i += 8) {
        const float4 r0 = *(const float4*)(x + (size_t)i * HDIM + 4 * lane);
        const float4 r1 = *(const float4*)(x + (size_t)(i + 4) * HDIM + 4 * lane);
        p0 += r0.x + r1.x; p1 += r0.y + r1.y; p2 += r0.z + r1.z; p3 += r0.w + r1.w;
        float pa = r0.x * v0 + r0.y * v1 + r0.z * v2 + r0.w * v3;
        float pb = r1.x * v0 + r1.y * v1 + r1.z * v2 + r1.w * v3;
        #pragma unroll
        for (int off = 32; off > 0; off >>= 1) {
            pa += __shfl_down(pa, off, 64);
            pb += __shfl_down(pb, off, 64);
        }
        if (lane == 0) {
            s[i] = pa; s[i + 4] = pb;
            if (inl) { s_loc[i - lo] = pa; s_loc[i + 4 - lo] = pb; }
            sm = fmaxf(sm, fmaxf(pa, pb));
        }
    }
    for (; i < hi; i += 4) {
        const float4 r0 = *(const float4*)(x + (size_t)i * HDIM + 4 * lane);
        p0 += r0.x; p1 += r0.y; p2 += r0.z; p3 += r0.w;
        float pa = r0.x * v0 + r0.y * v1 + r0.z * v2 + r0.w * v3;
        #pragma unroll
        for (int off = 32; off > 0; off >>= 1) pa += __shfl_down(pa, off, 64);
        if (lane == 0) {
            s[i] = pa;
            if (inl) s_loc[i - lo] = pa;
            sm = fmaxf(sm, pa);
        }
    }
    comb[wave][4 * lane + 0] = p0; comb[wave][4 * lane + 1] = p1;
    comb[wave][4 * lane + 2] = p2; comb[wave][4 * lane + 3] = p3;
    if (lane == 0) sred[wave] = sm;
    __syncthreads();
    float st0 = comb[0][t] + comb[1][t] + comb[2][t] + comb[3][t];
    stt[(size_t)b * HDIM + t] = st0;
    float smx = fmaxf(fmaxf(sred[0], sred[1]), fmaxf(sred[2], sred[3]));
    if (t == 0) smax[b] = smx;
    red[t] = st0 * u[t];
    __syncthreads();
    for (int st = 128; st > 0; st >>= 1) { if (t < st) red[t] += red[t + st]; __syncthreads(); }
    float d1 = red[0];
    __syncthreads();
    float M = smx + d1;
    M = M > 0.f ? M : 0.01f * M;

    // ---- pass 2: weighted aggregation, 4-row unroll (no shuffles) ----
    float a0 = 0.f, a1 = 0.f, a2 = 0.f, a3 = 0.f, den = 0.f;
    i = lo + wave;
    for (; i + 12 < hi; i += 16) {
        float s0v = inl ? s_loc[i - lo]      : s[i];
        float s1v = inl ? s_loc[i + 4 - lo]  : s[i + 4];
        float s2v = inl ? s_loc[i + 8 - lo]  : s[i + 8];
        float s3v = inl ? s_loc[i + 12 - lo] : s[i + 12];
        float e0 = s0v + d1; e0 = e0 > 0.f ? e0 : 0.01f * e0;
        float e1 = s1v + d1; e1 = e1 > 0.f ? e1 : 0.01f * e1;
        float e2 = s2v + d1; e2 = e2 > 0.f ? e2 : 0.01f * e2;
        float e3 = s3v + d1; e3 = e3 > 0.f ? e3 : 0.01f * e3;
        float w0 = __expf(e0 - M), w1 = __expf(e1 - M);
        float w2 = __expf(e2 - M), w3 = __expf(e3 - M);
        const float4 r0 = *(const float4*)(x + (size_t)i * HDIM + 4 * lane);
        const float4 r1 = *(const float4*)(x + (size_t)(i + 4) * HDIM + 4 * lane);
        const float4 r2 = *(const float4*)(x + (size_t)(i + 8) * HDIM + 4 * lane);
        const float4 r3 = *(const float4*)(x + (size_t)(i + 12) * HDIM + 4 * lane);
        den += (w0 + w1) + (w2 + w3);
        a0 += w0 * r0.x + w1 * r1.x + w2 * r2.x + w3 * r3.x;
        a1 += w0 * r0.y + w1 * r1.y + w2 * r2.y + w3 * r3.y;
        a2 += w0 * r0.z + w1 * r1.z + w2 * r2.z + w3 * r3.z;
        a3 += w0 * r0.w + w1 * r1.w + w2 * r2.w + w3 * r3.w;
    }
    for (; i < hi; i += 4) {
        float s0v = inl ? s_loc[i - lo] : s[i];
        float e0 = s0v + d1; e0 = e0 > 0.f ? e0 : 0.01f * e0;
        float w0 = __expf(e0 - M);
        const float4 r0 = *(const float4*)(x + (size_t)i * HDIM + 4 * lane);
        den += w0;
        a0 += w0 * r0.x; a1 += w0 * r0.y; a2 += w0 * r0.z; a3 += w0 * r0.w;
    }
    __syncthreads();
    comb[wave][4 * lane + 0] = a0; comb[wave][4 * lane + 1] = a1;
    comb[wave][4 * lane + 2] = a2; comb[wave][4 * lane + 3] = a3;
    if (lane == 0) dred[wave] = den;
    __syncthreads();
    float dtot = dred[0] + dred[1] + dred[2] + dred[3];
    float inv = (hi > lo) ? 1.0f / dtot : 0.f;
    __shared__ float ax[HDIM];
    ax[t] = (comb[0][t] + comb[1][t] + comb[2][t] + comb[3][t]) * inv;
    __syncthreads();
    float acc = bias_gat[t];
    #pragma unroll 8
    for (int ii = 0; ii < HDIM; ++ii) acc += ax[ii] * W[(size_t)ii * HDIM + t];
    hbuf[(size_t)b * HDIM + t] = acc > 0.f ? acc : expm1f(acc);
}

// ---------------------------------------------------------------------------
// k_iter2: tstep 2. GRU at head, then weighted sweep (s precomputed), then h2.
__global__ __launch_bounds__(256) void k_iter2(const float* __restrict__ x,
        const int* __restrict__ seg, const float* __restrict__ s,
        const float* __restrict__ u, const float* __restrict__ smax,
        float* __restrict__ stt,
        const float* __restrict__ gi, const float* __restrict__ gh,
        const float* __restrict__ b_ih, const float* __restrict__ b_hh,
        const float* __restrict__ W, const float* __restrict__ bias_gat,
        float* __restrict__ hbuf) {
    int b = blockIdx.x, t = threadIdx.x;
    int lo = seg[b], hi = seg[b + 1];
    size_t base = (size_t)b * (3 * HDIM);
    float gir = gi[base + t] + b_ih[t];
    float giz = gi[base + HDIM + t] + b_ih[HDIM + t];
    float gin = gi[base + 2 * HDIM + t] + b_ih[2 * HDIM + t];
    float ghr = gh[base + t] + b_hh[t];
    float ghz = gh[base + HDIM + t] + b_hh[HDIM + t];
    float ghn = gh[base + 2 * HDIM + t] + b_hh[2 * HDIM + t];
    float r = 1.f / (1.f + __expf(-(gir + ghr)));
    float z = 1.f / (1.f + __expf(-(giz + ghz)));
    float n = tanhf(gin + r * ghn);
    float prev = stt[(size_t)b * HDIM + t];
    float h2 = (1.f - z) * n + z * prev;
    float st_j = h2 / (1.f + __expf(-h2));
    stt[(size_t)b * HDIM + t] = st_j;

    __shared__ float red[256];
    red[t] = st_j * u[t];
    __syncthreads();
    for (int st = 128; st > 0; st >>= 1) { if (t < st) red[t] += red[t + st]; __syncthreads(); }
    float d2 = red[0];
    __syncthreads();
    float M = smax[b] + d2;
    M = M > 0.f ? M : 0.01f * M;

    int wave = t >> 6, lane = t & 63;
    float a0 = 0.f, a1 = 0.f, a2 = 0.f, a3 = 0.f, den = 0.f;
    int i = lo + wave;
    for (; i + 12 < hi; i += 16) {
        float e0 = s[i] + d2;      e0 = e0 > 0.f ? e0 : 0.01f * e0;
        float e1 = s[i + 4] + d2;  e1 = e1 > 0.f ? e1 : 0.01f * e1;
        float e2 = s[i + 8] + d2;  e2 = e2 > 0.f ? e2 : 0.01f * e2;
        float e3 = s[i + 12] + d2; e3 = e3 > 0.f ? e3 : 0.01f * e3;
        float w0 = __expf(e0 - M), w1 = __expf(e1 - M);
        float w2 = __expf(e2 - M), w3 = __expf(e3 - M);
        const float4 r0 = *(const float4*)(x + (size_t)i * HDIM + 4 * lane);
        const float4 r1 = *(const float4*)(x + (size_t)(i + 4) * HDIM + 4 * lane);
        const float4 r2 = *(const float4*)(x + (size_t)(i + 8) * HDIM + 4 * lane);
        const float4 r3 = *(const float4*)(x + (size_t)(i + 12) * HDIM + 4 * lane);
        den += (w0 + w1) + (w2 + w3);
        a0 += w0 * r0.x + w1 * r1.x + w2 * r2.x + w3 * r3.x;
        a1 += w0 * r0.y + w1 * r1.y + w2 * r2.y + w3 * r3.y;
        a2 += w0 * r0.z + w1 * r1.z + w2 * r2.z + w3 * r3.z;
        a3 += w0 * r0.w + w1 * r1.w + w2 * r2.w + w3 * r3.w;
    }
    for (; i < hi; i += 4) {
        float e0 = s[i] + d2; e0 = e0 > 0.f ? e0 : 0.01f * e0;
        float w0 = __expf(e0 - M);
        const float4 r0 = *(const float4*)(x + (size_t)i * HDIM + 4 * lane);
        den += w0;
        a0 += w0 * r0.x; a1 += w0 * r0.y; a2 += w0 * r0.z; a3 += w0 * r0.w;
    }
    __shared__ float comb[4][HDIM];
    __shared__ float dred[4];
    comb[wave][4 * lane + 0] = a0; comb[wave][4 * lane + 1] = a1;
    comb[wave][4 * lane + 2] = a2; comb[wave][4 * lane + 3] = a3;
    if (lane == 0) dred[wave] = den;
    __syncthreads();
    float dtot = dred[0] + dred[1] + dred[2] + dred[3];
    float inv = (hi > lo) ? 1.0f / dtot : 0.f;
    __shared__ float ax[HDIM];
    ax[t] = (comb[0][t] + comb[1][t] + comb[2][t] + comb[3][t]) * inv;
    __syncthreads();
    float acc = bias_gat[t];
    #pragma unroll 8
    for (int ii = 0; ii < HDIM; ++ii) acc += ax[ii] * W[(size_t)ii * HDIM + t];
    hbuf[(size_t)b * HDIM + t] = acc > 0.f ? acc : expm1f(acc);
}

// ---------------------------------------------------------------------------
// MFMA dual GEMM: C[z][1024x768] = A[z] @ B[z]^T, B row-major [768,256].
// 64x64 tile, 4 waves; bf16 staged in LDS (pad 40), fp32 MFMA accumulate.
// Layouts (HW-verified): A-frag A[m=lane&15][k=quad*8+j]; B-frag mirrored
// (n=lane&15); C/D row=quad*4+r, col=lane&15.
__global__ __launch_bounds__(256) void k_gemm2m(const float* __restrict__ A0,
        const float* __restrict__ A1, const float* __restrict__ B0,
        const float* __restrict__ B1, float* __restrict__ C0, float* __restrict__ C1) {
    const int K = HDIM, N = 3 * HDIM;
    const float* A = blockIdx.z ? A1 : A0;
    const float* Bm = blockIdx.z ? B1 : B0;
    float* C = blockIdx.z ? C1 : C0;
    int m0 = blockIdx.x * 64, n0 = blockIdx.y * 64;
    __shared__ __align__(16) unsigned short As[64][40];
    __shared__ __align__(16) unsigned short Bs[64][40];
    int t = threadIdx.x;
    int wave = t >> 6, lane = t & 63;
    int quad = lane >> 4, l16 = lane & 15;
    f32x4 acc[4] = {};
    for (int k0 = 0; k0 < K; k0 += 32) {
        int r = t >> 2;
        int kq = (t & 3) << 3;
        float4 av0 = *(const float4*)(A + (size_t)(m0 + r) * K + k0 + kq);
        float4 av1 = *(const float4*)(A + (size_t)(m0 + r) * K + k0 + kq + 4);
        short8 pa;
        pa[0] = (short)f2bf(av0.x); pa[1] = (short)f2bf(av0.y);
        pa[2] = (short)f2bf(av0.z); pa[3] = (short)f2bf(av0.w);
        pa[4] = (short)f2bf(av1.x); pa[5] = (short)f2bf(av1.y);
        pa[6] = (short)f2bf(av1.z); pa[7] = (short)f2bf(av1.w);
        *(short8*)&As[r][kq] = pa;
        float4 bv0 = *(const float4*)(Bm + (size_t)(n0 + r) * K + k0 + kq);
        float4 bv1 = *(const float4*)(Bm + (size_t)(n0 + r) * K + k0 + kq + 4);
        short8 pb;
        pb[0] = (short)f2bf(bv0.x); pb[1] = (short)f2bf(bv0.y);
        pb[2] = (short)f2bf(bv0.z); pb[3] = (short)f2bf(bv0.w);
        pb[4] = (short)f2bf(bv1.x); pb[5] = (short)f2bf(bv1.y);
        pb[6] = (short)f2bf(bv1.z); pb[7] = (short)f2bf(bv1.w);
        *(short8*)&Bs[r][kq] = pb;
        __syncthreads();
        short8 a = *(const short8*)&As[wave * 16 + l16][quad * 8];
        #pragma unroll
        for (int tn = 0; tn < 4; ++tn) {
            short8 bfr = *(const short8*)&Bs[tn * 16 + l16][quad * 8];
            acc[tn] = __builtin_amdgcn_mfma_f32_16x16x32_bf16(a, bfr, acc[tn], 0, 0, 0);
        }
        __syncthreads();
    }
    #pragma unroll
    for (int tn = 0; tn < 4; ++tn)
        #pragma unroll
        for (int rr = 0; rr < 4; ++rr)
            C[(size_t)(m0 + wave * 16 + quad * 4 + rr) * N + n0 + tn * 16 + l16] = acc[tn][rr];
}

// ---------------------------------------------------------------------------
// Final: out = GRU(gi, gh, stt) @ W_lin + b_lin (fp32 VALU; GRU in A-loader).
__global__ __launch_bounds__(256) void k_final(const float* __restrict__ gi,
        const float* __restrict__ gh, const float* __restrict__ b_ih,
        const float* __restrict__ b_hh, const float* __restrict__ stt,
        const float* __restrict__ B, const float* __restrict__ bias,
        float* __restrict__ C, int M, int N, int K) {
    __shared__ __align__(16) float As[16][64];
    __shared__ __align__(16) float Bs[16][64];
    int tx = threadIdx.x & 15, ty = threadIdx.x >> 4;
    int m0 = blockIdx.x * 64, n0 = blockIdx.y * 64;
    float acc[4][4] = {};
    for (int k0 = 0; k0 < K; k0 += 16) {
        {
            int r = threadIdx.x >> 2;
            int kk0 = (threadIdx.x & 3) << 2;
            int mrow = m0 + r;
            size_t base = (size_t)mrow * (3 * HDIM);
            #pragma unroll
            for (int q = 0; q < 4; ++q) {
                int k = k0 + kk0 + q;
                float gir = gi[base + k] + b_ih[k];
                float giz = gi[base + HDIM + k] + b_ih[HDIM + k];
                float gin = gi[base + 2 * HDIM + k] + b_ih[2 * HDIM + k];
                float ghr = gh[base + k] + b_hh[k];
                float ghz = gh[base + HDIM + k] + b_hh[HDIM + k];
                float ghn = gh[base + 2 * HDIM + k] + b_hh[2 * HDIM + k];
                float rg = 1.f / (1.f + __expf(-(gir + ghr)));
                float zg = 1.f / (1.f + __expf(-(giz + ghz)));
                float ng = tanhf(gin + rg * ghn);
                float prev = stt[(size_t)mrow * HDIM + k];
                float h2 = (1.f - zg) * ng + zg * prev;
                As[kk0 + q][r] = h2 / (1.f + __expf(-h2));
            }
        }
        {
            int kk = threadIdx.x >> 4;
            int nn = (threadIdx.x & 15) << 2;
            float4 bv = *(const float4*)(B + (size_t)(k0 + kk) * N + n0 + nn);
            Bs[kk][nn + 0] = bv.x; Bs[kk][nn + 1] = bv.y;
            Bs[kk][nn + 2] = bv.z; Bs[kk][nn + 3] = bv.w;
        }
        __syncthreads();
        #pragma unroll
        for (int kk = 0; kk < 16; ++kk) {
            float4 a = *(const float4*)&As[kk][ty * 4];
            float4 bb = *(const float4*)&Bs[kk][tx * 4];
            acc[0][0] += a.x * bb.x; acc[0][1] += a.x * bb.y; acc[0][2] += a.x * bb.z; acc[0][3] += a.x * bb.w;
            acc[1][0] += a.y * bb.x; acc[1][1] += a.y * bb.y; acc[1][2] += a.y * bb.z; acc[1][3] += a.y * bb.w;
            acc[2][0] += a.z * bb.x; acc[2][1] += a.z * bb.y; acc[2][2] += a.z * bb.z; acc[2][3] += a.z * bb.w;
            acc[3][0] += a.w * bb.x; acc[3][1] += a.w * bb.y; acc[3][2] += a.w * bb.z; acc[3][3] += a.w * bb.w;
        }
        __syncthreads();
    }
    float bsv[4];
    #pragma unroll
    for (int j = 0; j < 4; ++j) bsv[j] = bias[n0 + tx * 4 + j];
    #pragma unroll
    for (int i = 0; i < 4; ++i) {
        int mrow = m0 + ty * 4 + i;
        *(float4*)(C + (size_t)mrow * N + n0 + tx * 4) =
            make_float4(acc[i][0] + bsv[0], acc[i][1] + bsv[1],
                        acc[i][2] + bsv[2], acc[i][3] + bsv[3]);
    }
}

extern "C" void kernel_launch(void* const* d_in, const int* in_sizes, int n_in,
                              void* d_out, int out_size, void* d_ws, size_t ws_size,
                              hipStream_t stream) {
    const float* x        = (const float*)d_in[0];
    const int*   batch    = (const int*)d_in[1];
    const float* W        = (const float*)d_in[2];
    const float* att_src  = (const float*)d_in[3];
    const float* att_dst  = (const float*)d_in[4];
    const float* bias_gat = (const float*)d_in[5];
    const float* W_ih     = (const float*)d_in[6];
    const float* W_hh     = (const float*)d_in[7];
    const float* b_ih     = (const float*)d_in[8];
    const float* b_hh     = (const float*)d_in[9];
    const float* W_lin    = (const float*)d_in[10];
    const float* b_lin    = (const float*)d_in[11];

    char* ws = (char*)d_ws;
    size_t off = 0;
    auto alloc = [&](size_t bytes) {
        void* p = (void*)(ws + off);
        off += (bytes + 255) & ~(size_t)255;
        return p;
    };
    int*   seg  = (int*)alloc((BGRAPH + 1) * 4);
    float* vv   = (float*)alloc(HDIM * 4);
    float* uu   = (float*)alloc(HDIM * 4);
    float* smax = (float*)alloc(BGRAPH * 4);
    float* s    = (float*)alloc((size_t)N_NODES * 4);
    float* stt  = (float*)alloc((size_t)BGRAPH * HDIM * 4);
    float* hbuf = (float*)alloc((size_t)BGRAPH * HDIM * 4);
    float* gi   = (float*)alloc((size_t)BGRAPH * 3 * HDIM * 4);
    float* gh   = (float*)alloc((size_t)BGRAPH * 3 * HDIM * 4);

    hipLaunchKernelGGL(k_prep, dim3(261), dim3(256), 0, stream,
                       W, att_src, att_dst, batch, vv, uu, seg);
    // tstep 1 fused with pool pass
    hipLaunchKernelGGL(k_passAB, dim3(BGRAPH), dim3(256), 0, stream,
                       x, seg, vv, uu, W, bias_gat, s, smax, stt, hbuf);
    hipLaunchKernelGGL(k_gemm2m, dim3(BGRAPH / 64, (3 * HDIM) / 64, 2), dim3(256), 0,
                       stream, hbuf, stt, W_ih, W_hh, gi, gh);
    // tstep 2 (GRU folded into head, s precomputed)
    hipLaunchKernelGGL(k_iter2, dim3(BGRAPH), dim3(256), 0, stream,
                       x, seg, s, uu, smax, stt, gi, gh, b_ih, b_hh, W, bias_gat, hbuf);
    hipLaunchKernelGGL(k_gemm2m, dim3(BGRAPH / 64, (3 * HDIM) / 64, 2), dim3(256), 0,
                       stream, hbuf, stt, W_ih, W_hh, gi, gh);
    // final: GRU folded into A-loader, then @ W_lin + b_lin
    hipLaunchKernelGGL(k_final, dim3(BGRAPH / 64, ODIM / 64), dim3(256), 0, stream,
                       gi, gh, b_ih, b_hh, stt, W_lin, b_lin, (float*)d_out,
                       BGRAPH, ODIM, HDIM);
}